// Round 3
// baseline (3876.392 us; speedup 1.0000x reference)
//
#include <hip/hip_runtime.h>
#include <hip/hip_bf16.h>
#include <cstdint>

#define SENT_LEN   256
#define SENT_BATCH 64
#define WORD_LEN   16
#define EMB        128
#define HID        256
#define CEMB       64
#define CHID       128
#define TAGS       50
#define K_IN       (EMB + CHID)   // 256

typedef __attribute__((ext_vector_type(8))) short short8;
typedef __attribute__((ext_vector_type(4))) float f32x4;
typedef __attribute__((ext_vector_type(4))) int   i32x4;

__device__ __forceinline__ float sigf(float x) {
    return 1.f / (1.f + __expf(-x));
}
__device__ __forceinline__ float tanhf_fast(float x) {
    x = fminf(fmaxf(x, -15.f), 15.f);
    float e = __expf(2.f * x);
    return (e - 1.f) / (e + 1.f);
}
__device__ __forceinline__ float bf_lo(unsigned u) { return __uint_as_float(u << 16); }
__device__ __forceinline__ float bf_hi(unsigned u) { return __uint_as_float(u & 0xffff0000u); }
__device__ __forceinline__ unsigned short f2bfu(float f) {
    __hip_bfloat16 h = __float2bfloat16(f);
    return *reinterpret_cast<unsigned short*>(&h);
}

// ---------------- K1a: pre4[ch][jj][gt] = b_c[g] + sum_k Wih_c[g][k]*char_emb[ch][k], g = gt*128+jj
__global__ void prep_char(const float* __restrict__ Wih_c, const float* __restrict__ char_emb,
                          const float* __restrict__ bih_c, const float* __restrict__ bhh_c,
                          float* __restrict__ pre4) {
    int ch = blockIdx.x;      // 128
    int g  = threadIdx.x;     // 512
    float acc = bih_c[g] + bhh_c[g];
    const float* w = Wih_c + g * CEMB;
    const float* e = char_emb + ch * CEMB;
#pragma unroll
    for (int k = 0; k < CEMB; k++) acc += w[k] * e[k];
    pre4[ch * 512 + (g & 127) * 4 + (g >> 7)] = acc;
}

// ---------------- K1b: per-row i8 quantization of Whh_w. 1024 blocks x 64 (one wave per row).
__global__ void prep_wq(const float* __restrict__ Whh_w, signed char* __restrict__ wq,
                        float* __restrict__ sw) {
    int g = blockIdx.x;
    int lane = threadIdx.x;   // 64
    float4 v = reinterpret_cast<const float4*>(Whh_w + (size_t)g * HID)[lane];
    float m = fmaxf(fmaxf(fabsf(v.x), fabsf(v.y)), fmaxf(fabsf(v.z), fabsf(v.w)));
#pragma unroll
    for (int off = 32; off; off >>= 1) m = fmaxf(m, __shfl_xor(m, off, 64));
    m = fmaxf(m, 1e-20f);
    float inv = 127.f / m;
    int q0 = __float2int_rn(v.x * inv), q1 = __float2int_rn(v.y * inv);
    int q2 = __float2int_rn(v.z * inv), q3 = __float2int_rn(v.w * inv);
    int packed = (q0 & 255) | ((q1 & 255) << 8) | ((q2 & 255) << 16) | ((q3 & 255) << 24);
    reinterpret_cast<int*>(wq)[g * 64 + lane] = packed;
    if (lane == 0) sw[g] = m / 127.f;
}

// ---------------- K2: char LSTM. 16 blocks x 16 chains, 512 threads (8 waves).
// Whh_c bf16 register-resident (wave w owns gates [w*64, w*64+64)); h round-trips
// through a 4KB LDS A-pack in MFMA A-fragment order. No cross-block traffic.
__global__ __launch_bounds__(512, 2) void char_lstm(
        const int* __restrict__ words, const float* __restrict__ Whh_c,
        const float* __restrict__ pre4, float* __restrict__ cf) {
    int cb   = blockIdx.x;               // chains t in [cb*16, cb*16+16)
    int tid  = threadIdx.x;
    int lane = tid & 63, w = tid >> 6;   // 8 waves
    int l15  = lane & 15, lq = lane >> 4;

    __shared__ short8 ha[4 * 64];        // A-pack [kt][lane], bf16, 4 KB
    __shared__ float  g_s[4][16][132];   // [gate_type][chain][jj], padded, 33 KB
    __shared__ int    cid_s[16];

    // B-frags: wave w gates w*64 + nt*16 + l15; k = kt*32 + lq*8 + j
    short8 bfr[4][4];
#pragma unroll
    for (int nt = 0; nt < 4; nt++) {
        int g = w * 64 + nt * 16 + l15;
        const float* wr = Whh_c + (size_t)g * CHID;
#pragma unroll
        for (int kt = 0; kt < 4; kt++) {
            float4 v0 = reinterpret_cast<const float4*>(wr + kt * 32 + lq * 8)[0];
            float4 v1 = reinterpret_cast<const float4*>(wr + kt * 32 + lq * 8 + 4)[0];
            short8 b;
            b[0] = (short)f2bfu(v0.x); b[1] = (short)f2bfu(v0.y);
            b[2] = (short)f2bfu(v0.z); b[3] = (short)f2bfu(v0.w);
            b[4] = (short)f2bfu(v1.x); b[5] = (short)f2bfu(v1.y);
            b[6] = (short)f2bfu(v1.z); b[7] = (short)f2bfu(v1.w);
            bfr[nt][kt] = b;
        }
    }
    {
        short8 z = {0, 0, 0, 0, 0, 0, 0, 0};
        for (int i = tid; i < 256; i += 512) ha[i] = z;
    }
    float cst[8] = {0.f, 0.f, 0.f, 0.f, 0.f, 0.f, 0.f, 0.f};
    int nb  = tid >> 4;          // nonlin (threads < 256): chain
    int jj0 = (tid & 15) * 8;    // 8 consecutive hidden dims
    __syncthreads();

    for (int s = 0; s < SENT_BATCH * WORD_LEN; s++) {
        if (tid < 16) cid_s[tid] = words[s * SENT_LEN + cb * 16 + tid];
        // ---- GEMM: gates_partial = h_{s-1} @ Whh_c^T
        f32x4 acc[4] = {{0.f,0.f,0.f,0.f},{0.f,0.f,0.f,0.f},{0.f,0.f,0.f,0.f},{0.f,0.f,0.f,0.f}};
#pragma unroll
        for (int kt = 0; kt < 4; kt++) {
            short8 a = ha[kt * 64 + lane];
#pragma unroll
            for (int nt = 0; nt < 4; nt++)
                acc[nt] = __builtin_amdgcn_mfma_f32_16x16x32_bf16(a, bfr[nt][kt], acc[nt], 0, 0, 0);
        }
        // ---- scatter to [gate_type][chain][jj]  (C layout: row=chain=lq*4+r, col=l15)
#pragma unroll
        for (int nt = 0; nt < 4; nt++) {
            int g = w * 64 + nt * 16 + l15;
            int gt = g >> 7, jj = g & 127;
#pragma unroll
            for (int r = 0; r < 4; r++)
                g_s[gt][lq * 4 + r][jj] = acc[nt][r];
        }
        __syncthreads();
        // ---- nonlinearity: thread (chain nb, dims jj0..jj0+7)
        if (tid < 256) {
            int cid = cid_s[nb];
            const float4* pp = reinterpret_cast<const float4*>(pre4 + ((size_t)cid * 128 + jj0) * 4);
            short8 hv;
            float hbuf[8];
#pragma unroll
            for (int p = 0; p < 8; p++) {
                int jj = jj0 + p;
                float4 pr = pp[p];
                float gi = sigf(g_s[0][nb][jj] + pr.x);
                float gf = sigf(g_s[1][nb][jj] + pr.y);
                float gg = tanhf_fast(g_s[2][nb][jj] + pr.z);
                float go = sigf(g_s[3][nb][jj] + pr.w);
                float c = gf * cst[p] + gi * gg;
                cst[p] = c;
                float h = go * tanhf_fast(c);
                hbuf[p] = h;
                hv[p] = (short)f2bfu(h);
            }
            ha[(jj0 >> 5) * 64 + ((jj0 >> 3) & 3) * 16 + nb] = hv;
            if ((s & 15) == 15) {
                float* cp = cf + (size_t)(cb * 16 + nb) * (SENT_BATCH * CHID) + (s >> 4) * CHID + jj0;
                float4 o0 = {hbuf[0], hbuf[1], hbuf[2], hbuf[3]};
                float4 o1 = {hbuf[4], hbuf[5], hbuf[6], hbuf[7]};
                reinterpret_cast<float4*>(cp)[0] = o0;
                reinterpret_cast<float4*>(cp)[1] = o1;
            }
        }
        __syncthreads();
    }
}

// ---------------- K3: xw4[tb][jj][gt] = bf16( b_w[g] + sum_k x[tb][k]*Wih_w[g][k] ), g = gt*256+jj
#define BM 64
#define BN 128
#define BK 32
__global__ __launch_bounds__(256) void xw_gemm(
        const int* __restrict__ sentences, const float* __restrict__ word_emb,
        const float* __restrict__ cf, const float* __restrict__ Wih_w,
        const float* __restrict__ bih_w, const float* __restrict__ bhh_w,
        unsigned short* __restrict__ xw4) {
    __shared__ float A_s[BM][BK + 1];
    __shared__ float B_s[BK][BN + 4];
    __shared__ int sid_s[BM];
    int tid = threadIdx.x;
    int row0 = blockIdx.y * BM;
    int col0 = blockIdx.x * BN;
    if (tid < BM) sid_s[tid] = sentences[row0 + tid];
    __syncthreads();

    float acc[8][4] = {};
    int tx = tid & 31, tyy = tid >> 5;

    for (int k0 = 0; k0 < K_IN; k0 += BK) {
#pragma unroll
        for (int i = 0; i < 2; i++) {
            int idx = tid + i * 256;
            int r = idx >> 3, k4 = idx & 7;
            int k = k0 + k4 * 4;
            float4 v;
            if (k < EMB)
                v = reinterpret_cast<const float4*>(word_emb + (size_t)sid_s[r] * EMB + k)[0];
            else
                v = reinterpret_cast<const float4*>(cf + (size_t)(row0 + r) * CHID + (k - EMB))[0];
            A_s[r][k4 * 4 + 0] = v.x; A_s[r][k4 * 4 + 1] = v.y;
            A_s[r][k4 * 4 + 2] = v.z; A_s[r][k4 * 4 + 3] = v.w;
        }
#pragma unroll
        for (int i = 0; i < 4; i++) {
            int idx = tid + i * 256;
            int gg = idx >> 3, k4 = idx & 7;
            float4 v = reinterpret_cast<const float4*>(Wih_w + (size_t)(col0 + gg) * K_IN + k0 + k4 * 4)[0];
            B_s[k4 * 4 + 0][gg] = v.x; B_s[k4 * 4 + 1][gg] = v.y;
            B_s[k4 * 4 + 2][gg] = v.z; B_s[k4 * 4 + 3][gg] = v.w;
        }
        __syncthreads();
#pragma unroll
        for (int kk = 0; kk < BK; kk++) {
            float4 bv = reinterpret_cast<const float4*>(&B_s[kk][tx * 4])[0];
#pragma unroll
            for (int i = 0; i < 8; i++) {
                float av = A_s[tyy * 8 + i][kk];
                acc[i][0] += av * bv.x; acc[i][1] += av * bv.y;
                acc[i][2] += av * bv.z; acc[i][3] += av * bv.w;
            }
        }
        __syncthreads();
    }
#pragma unroll
    for (int i = 0; i < 8; i++) {
        int r = row0 + tyy * 8 + i;
#pragma unroll
        for (int j = 0; j < 4; j++) {
            int cg = col0 + tx * 4 + j;
            xw4[(size_t)r * 1024 + (cg & 255) * 4 + (cg >> 8)] =
                f2bfu(acc[i][j] + bih_w[cg] + bhh_w[cg]);
        }
    }
}

// ---------------- K4: word LSTM. 4 blocks x 16 chains, 512 threads (8 waves).
// Whh_w i8 register-resident (wave w owns gates [w*128, w*128+128), per-row scales);
// h quantized h*127 (|h|<1) into 4KB LDS A-pack. mfma_i32_16x16x32_i8. No sync.
__global__ __launch_bounds__(512, 2) void word_lstm(
        const unsigned short* __restrict__ xw4, const signed char* __restrict__ wq,
        const float* __restrict__ sw, float* __restrict__ h_out) {
    int wb   = blockIdx.x;               // chains [wb*16, wb*16+16)
    int tid  = threadIdx.x;
    int lane = tid & 63, w = tid >> 6;   // 8 waves
    int l15  = lane & 15, lq = lane >> 4;

    __shared__ long  ha[8 * 64];         // A-pack [kt][lane], 8 i8 each, 4 KB
    __shared__ float g_s[4][16][260];    // [gate_type][chain][jj], padded, 66.5 KB

    long bfr[8][8];
    float swl[8];
#pragma unroll
    for (int nt = 0; nt < 8; nt++) {
        int g = w * 128 + nt * 16 + l15;
        swl[nt] = sw[g] * (1.f / 127.f);
#pragma unroll
        for (int kt = 0; kt < 8; kt++)
            bfr[nt][kt] = *reinterpret_cast<const long*>(wq + (size_t)g * HID + kt * 32 + lq * 8);
    }
    for (int i = tid; i < 512; i += 512) ha[i] = 0;
    float cst[8] = {0.f, 0.f, 0.f, 0.f, 0.f, 0.f, 0.f, 0.f};
    int nb  = tid >> 5;          // nonlin: chain (0..15)
    int jj0 = (tid & 31) * 8;    // 8 consecutive hidden dims
    __syncthreads();

    for (int t = 0; t < SENT_LEN; t++) {
        i32x4 acc[8] = {};
#pragma unroll
        for (int kt = 0; kt < 8; kt++) {
            long a = ha[kt * 64 + lane];
#pragma unroll
            for (int nt = 0; nt < 8; nt++)
                acc[nt] = __builtin_amdgcn_mfma_i32_16x16x32_i8(a, bfr[nt][kt], acc[nt], 0, 0, 0);
        }
#pragma unroll
        for (int nt = 0; nt < 8; nt++) {
            int g = w * 128 + nt * 16 + l15;
            int gt = g >> 8, jj = g & 255;
#pragma unroll
            for (int r = 0; r < 4; r++)
                g_s[gt][lq * 4 + r][jj] = (float)acc[nt][r] * swl[nt];
        }
        __syncthreads();
        // ---- nonlinearity: thread (chain nb, dims jj0..jj0+7)
        {
            int bg = wb * 16 + nb;
            const uint2* xp = reinterpret_cast<const uint2*>(
                xw4 + (((size_t)t * SENT_BATCH + bg) * 256 + jj0) * 4);
            float hbuf[8];
            int qlo = 0, qhi = 0;
#pragma unroll
            for (int p = 0; p < 8; p++) {
                int jj = jj0 + p;
                uint2 q = xp[p];
                float gi = sigf(g_s[0][nb][jj] + bf_lo(q.x));
                float gf = sigf(g_s[1][nb][jj] + bf_hi(q.x));
                float gg = tanhf_fast(g_s[2][nb][jj] + bf_lo(q.y));
                float go = sigf(g_s[3][nb][jj] + bf_hi(q.y));
                float c = gf * cst[p] + gi * gg;
                cst[p] = c;
                float h = go * tanhf_fast(c);
                hbuf[p] = h;
                int qi = __float2int_rn(h * 127.f);
                qi = qi > 127 ? 127 : (qi < -127 ? -127 : qi);
                if (p < 4) qlo |= (qi & 255) << (8 * p);
                else       qhi |= (qi & 255) << (8 * (p - 4));
            }
            long packed = (long)(unsigned)qlo | ((long)qhi << 32);
            ha[(jj0 >> 5) * 64 + ((jj0 >> 3) & 3) * 16 + nb] = packed;
            float* hp = h_out + ((size_t)t * SENT_BATCH + bg) * HID + jj0;
            float4 o0 = {hbuf[0], hbuf[1], hbuf[2], hbuf[3]};
            float4 o1 = {hbuf[4], hbuf[5], hbuf[6], hbuf[7]};
            reinterpret_cast<float4*>(hp)[0] = o0;
            reinterpret_cast<float4*>(hp)[1] = o1;
        }
        __syncthreads();
    }
}

// ---------------- K5: tag projection + log_softmax.
__global__ __launch_bounds__(256) void tag_logsoftmax(
        const float* __restrict__ h_out, const float* __restrict__ W_tag,
        const float* __restrict__ b_tag, float* __restrict__ out) {
    __shared__ float wt_s[TAGS * 257];
    __shared__ float hr_s[4 * HID];
    int tid = threadIdx.x;
    int row0 = blockIdx.x * 4;
#pragma unroll 2
    for (int i = 0; i < TAGS; i++) wt_s[i * 257 + tid] = W_tag[i * HID + tid];
#pragma unroll
    for (int w = 0; w < 4; w++) hr_s[w * HID + tid] = h_out[(size_t)(row0 + w) * HID + tid];
    __syncthreads();

    int w = tid >> 6, l = tid & 63;
    float acc = 0.f;
    if (l < TAGS) {
        acc = b_tag[l];
        const float* hr = hr_s + w * HID;
        const float* wr = wt_s + l * 257;
#pragma unroll 4
        for (int k = 0; k < HID; k++) acc += hr[k] * wr[k];
    }
    float m = (l < TAGS) ? acc : -1e30f;
#pragma unroll
    for (int off = 32; off; off >>= 1) m = fmaxf(m, __shfl_xor(m, off, 64));
    float e = (l < TAGS) ? __expf(acc - m) : 0.f;
    float ssum = e;
#pragma unroll
    for (int off = 32; off; off >>= 1) ssum += __shfl_xor(ssum, off, 64);
    float lse = m + __logf(ssum);
    if (l < TAGS) out[(size_t)(row0 + w) * TAGS + l] = acc - lse;
}

extern "C" void kernel_launch(void* const* d_in, const int* in_sizes, int n_in,
                              void* d_out, int out_size, void* d_ws, size_t ws_size,
                              hipStream_t stream) {
    (void)in_sizes; (void)n_in; (void)out_size; (void)ws_size;
    const int*   sentences = (const int*)d_in[0];
    const int*   words     = (const int*)d_in[1];
    const float* word_emb  = (const float*)d_in[4];
    const float* char_emb  = (const float*)d_in[5];
    const float* Wih_c     = (const float*)d_in[6];
    const float* Whh_c     = (const float*)d_in[7];
    const float* bih_c     = (const float*)d_in[8];
    const float* bhh_c     = (const float*)d_in[9];
    const float* Wih_w     = (const float*)d_in[10];
    const float* Whh_w     = (const float*)d_in[11];
    const float* bih_w     = (const float*)d_in[12];
    const float* bhh_w     = (const float*)d_in[13];
    const float* W_tag     = (const float*)d_in[14];
    const float* b_tag     = (const float*)d_in[15];
    float* out = (float*)d_out;

    char* ws = (char*)d_ws;
    size_t off = 0;
    float* pre4 = (float*)(ws + off);                 off += 512 * 128 * sizeof(float);      // 256 KB
    signed char* wq = (signed char*)(ws + off);       off += 1024 * 256;                     // 256 KB
    float* sw = (float*)(ws + off);                   off += 1024 * sizeof(float);           // 4 KB
    off = (off + 255) & ~(size_t)255;
    float* cf = (float*)(ws + off);                   off += (size_t)SENT_LEN * SENT_BATCH * CHID * sizeof(float); // 8.4 MB
    unsigned short* xw4 = (unsigned short*)(ws + off); off += (size_t)SENT_LEN * SENT_BATCH * 1024 * sizeof(unsigned short); // 33.5 MB
    float* h_out = (float*)(ws + off);                off += (size_t)SENT_LEN * SENT_BATCH * HID * sizeof(float); // 16.8 MB

    hipLaunchKernelGGL(prep_char, dim3(128), dim3(512), 0, stream,
                       Wih_c, char_emb, bih_c, bhh_c, pre4);
    hipLaunchKernelGGL(prep_wq, dim3(1024), dim3(64), 0, stream, Whh_w, wq, sw);
    hipLaunchKernelGGL(char_lstm, dim3(16), dim3(512), 0, stream,
                       words, Whh_c, pre4, cf);
    hipLaunchKernelGGL(xw_gemm, dim3(1024 / BN, (SENT_LEN * SENT_BATCH) / BM), dim3(256), 0, stream,
                       sentences, word_emb, cf, Wih_w, bih_w, bhh_w, xw4);
    hipLaunchKernelGGL(word_lstm, dim3(4), dim3(512), 0, stream,
                       xw4, wq, sw, h_out);
    hipLaunchKernelGGL(tag_logsoftmax, dim3((SENT_LEN * SENT_BATCH) / 4), dim3(256), 0, stream,
                       h_out, W_tag, b_tag, out);
}

// Round 4
// 3080.559 us; speedup vs baseline: 1.2583x; 1.2583x over previous
//
#include <hip/hip_runtime.h>
#include <hip/hip_bf16.h>
#include <cstdint>

#define SENT_LEN   256
#define SENT_BATCH 64
#define WORD_LEN   16
#define EMB        128
#define HID        256
#define CEMB       64
#define CHID       128
#define TAGS       50
#define K_IN       (EMB + CHID)   // 256

typedef __attribute__((ext_vector_type(8))) short short8;
typedef __attribute__((ext_vector_type(4))) float f32x4;
typedef __attribute__((ext_vector_type(4))) int   i32x4;

__device__ __forceinline__ float sigf(float x) {
    return 1.f / (1.f + __expf(-x));
}
__device__ __forceinline__ float tanhf_fast(float x) {
    x = fminf(fmaxf(x, -15.f), 15.f);
    float e = __expf(2.f * x);
    return (e - 1.f) / (e + 1.f);
}
__device__ __forceinline__ float bfu2f(unsigned short u) { return __uint_as_float(((unsigned)u) << 16); }
__device__ __forceinline__ unsigned short f2bfu(float f) {
    __hip_bfloat16 h = __float2bfloat16(f);
    return *reinterpret_cast<unsigned short*>(&h);
}

// ---------------- K1a: pre8[((ch*8 + w)*16 + l15)*4 + gt] = b_c[g] + Wih_c[g]·char_emb[ch]
// where g = gt*128 + w*16 + l15  (per-lane float4 = all 4 gates of one dim)
__global__ void prep_char(const float* __restrict__ Wih_c, const float* __restrict__ char_emb,
                          const float* __restrict__ bih_c, const float* __restrict__ bhh_c,
                          float* __restrict__ pre8) {
    int ch = blockIdx.x;      // 128
    int g  = threadIdx.x;     // 512
    float acc = bih_c[g] + bhh_c[g];
    const float* w = Wih_c + g * CEMB;
    const float* e = char_emb + ch * CEMB;
#pragma unroll
    for (int k = 0; k < CEMB; k++) acc += w[k] * e[k];
    int gt = g >> 7, j = g & 127;
    pre8[(((ch * 8) + (j >> 4)) * 16 + (j & 15)) * 4 + gt] = acc;
}

// ---------------- K1b: per-row i8 quantization of Whh_w. 1024 blocks x 64.
__global__ void prep_wq(const float* __restrict__ Whh_w, signed char* __restrict__ wq,
                        float* __restrict__ sw) {
    int g = blockIdx.x;
    int lane = threadIdx.x;   // 64
    float4 v = reinterpret_cast<const float4*>(Whh_w + (size_t)g * HID)[lane];
    float m = fmaxf(fmaxf(fabsf(v.x), fabsf(v.y)), fmaxf(fabsf(v.z), fabsf(v.w)));
#pragma unroll
    for (int off = 32; off; off >>= 1) m = fmaxf(m, __shfl_xor(m, off, 64));
    m = fmaxf(m, 1e-20f);
    float inv = 127.f / m;
    int q0 = __float2int_rn(v.x * inv), q1 = __float2int_rn(v.y * inv);
    int q2 = __float2int_rn(v.z * inv), q3 = __float2int_rn(v.w * inv);
    int packed = (q0 & 255) | ((q1 & 255) << 8) | ((q2 & 255) << 16) | ((q3 & 255) << 24);
    reinterpret_cast<int*>(wq)[g * 64 + lane] = packed;
    if (lane == 0) sw[g] = m / 127.f;
}

// ---------------- K2: char LSTM. 64 blocks x 4 chains, 512 threads (8 waves).
// Wave w owns all 4 gate types for dims j = w*16 + l15 (in-register nonlin, no gate LDS).
// Only h crosses waves: 4KB bf16 A-pack, double-buffered, ONE barrier/step.
__global__ __launch_bounds__(512, 1) void char_lstm(
        const int* __restrict__ words, const float* __restrict__ Whh_c,
        const float* __restrict__ pre8, float* __restrict__ cf) {
    int cb   = blockIdx.x;               // chains t in [cb*4, cb*4+4)
    int tid  = threadIdx.x;
    int lane = tid & 63, w = tid >> 6;   // 8 waves
    int l15  = lane & 15, lq = lane >> 4;

    __shared__ short8 ha[2][256];        // A-pack [kt][lane], double buffered, 8 KB

    // B-frags: nt = gate type; g = nt*128 + w*16 + l15; k = kt*32 + lq*8 + j
    short8 bfr[4][4];
#pragma unroll
    for (int nt = 0; nt < 4; nt++) {
        int g = nt * 128 + w * 16 + l15;
        const float* wr = Whh_c + (size_t)g * CHID;
#pragma unroll
        for (int kt = 0; kt < 4; kt++) {
            float4 v0 = reinterpret_cast<const float4*>(wr + kt * 32 + lq * 8)[0];
            float4 v1 = reinterpret_cast<const float4*>(wr + kt * 32 + lq * 8 + 4)[0];
            short8 b;
            b[0] = (short)f2bfu(v0.x); b[1] = (short)f2bfu(v0.y);
            b[2] = (short)f2bfu(v0.z); b[3] = (short)f2bfu(v0.w);
            b[4] = (short)f2bfu(v1.x); b[5] = (short)f2bfu(v1.y);
            b[6] = (short)f2bfu(v1.z); b[7] = (short)f2bfu(v1.w);
            bfr[nt][kt] = b;
        }
    }
    {   // zero both A-pack buffers (512 x 16B)
        float4 z = {0.f, 0.f, 0.f, 0.f};
        reinterpret_cast<float4*>(ha)[tid] = z;
    }
    float cst[4] = {0.f, 0.f, 0.f, 0.f};
    int cids[4];
#pragma unroll
    for (int r = 0; r < 4; r++) cids[r] = words[cb * 4 + r];
    int j = w * 16 + l15;
    __syncthreads();

    for (int s = 0; s < SENT_BATCH * WORD_LEN; s++) {
        // pre-activations for this step (cids prefetched last iteration; L2 latency
        // hidden behind the MFMA block below)
        float4 pr[4];
#pragma unroll
        for (int r = 0; r < 4; r++)
            pr[r] = reinterpret_cast<const float4*>(pre8)[(cids[r] * 8 + w) * 16 + l15];
        int snx = (s + 1) & (SENT_BATCH * WORD_LEN - 1);
#pragma unroll
        for (int r = 0; r < 4; r++) cids[r] = words[snx * SENT_LEN + cb * 4 + r];

        const short8* hc = ha[s & 1];
        f32x4 acc[4] = {{0.f,0.f,0.f,0.f},{0.f,0.f,0.f,0.f},{0.f,0.f,0.f,0.f},{0.f,0.f,0.f,0.f}};
#pragma unroll
        for (int kt = 0; kt < 4; kt++) {
            short8 a = hc[kt * 64 + lane];
#pragma unroll
            for (int nt = 0; nt < 4; nt++)
                acc[nt] = __builtin_amdgcn_mfma_f32_16x16x32_bf16(a, bfr[nt][kt], acc[nt], 0, 0, 0);
        }

        unsigned short* hn = reinterpret_cast<unsigned short*>(ha[(s + 1) & 1]);
        bool wr16 = ((s & 15) == 15);
#pragma unroll
        for (int r = 0; r < 4; r++) {           // chain = cb*4 + r  (C row lq*4+r; real at lq==0)
            float gi = acc[0][r] + pr[r].x;
            float gf = acc[1][r] + pr[r].y;
            float gg = acc[2][r] + pr[r].z;
            float go = acc[3][r] + pr[r].w;
            float c = sigf(gf) * cst[r] + sigf(gi) * tanhf_fast(gg);
            cst[r] = c;
            float h = sigf(go) * tanhf_fast(c);
            if (lq == 0) {
                // A-pack slot for (m=r, k=j): entry kt*64 + ((j>>3)&3)*16 + r, half j&7
                hn[(((j >> 5) * 64) + ((j >> 3) & 3) * 16 + r) * 8 + (j & 7)] = f2bfu(h);
                if (wr16)
                    cf[((size_t)(cb * 4 + r) * SENT_BATCH + (s >> 4)) * CHID + j] = h;
            }
        }
        __syncthreads();
    }
}

// ---------------- K3: xw6 layout: [t][wb][w][l15][nt][r] bf16, per-lane contiguous for K4.
#define BM 64
#define BN 128
#define BK 32
__global__ __launch_bounds__(256) void xw_gemm(
        const int* __restrict__ sentences, const float* __restrict__ word_emb,
        const float* __restrict__ cf, const float* __restrict__ Wih_w,
        const float* __restrict__ bih_w, const float* __restrict__ bhh_w,
        unsigned short* __restrict__ xw6) {
    __shared__ float A_s[BM][BK + 1];
    __shared__ float B_s[BK][BN + 4];
    __shared__ int sid_s[BM];
    int tid = threadIdx.x;
    int row0 = blockIdx.y * BM;
    int col0 = blockIdx.x * BN;
    if (tid < BM) sid_s[tid] = sentences[row0 + tid];
    __syncthreads();

    float acc[8][4] = {};
    int tx = tid & 31, tyy = tid >> 5;

    for (int k0 = 0; k0 < K_IN; k0 += BK) {
#pragma unroll
        for (int i = 0; i < 2; i++) {
            int idx = tid + i * 256;
            int r = idx >> 3, k4 = idx & 7;
            int k = k0 + k4 * 4;
            float4 v;
            if (k < EMB)
                v = reinterpret_cast<const float4*>(word_emb + (size_t)sid_s[r] * EMB + k)[0];
            else
                v = reinterpret_cast<const float4*>(cf + (size_t)(row0 + r) * CHID + (k - EMB))[0];
            A_s[r][k4 * 4 + 0] = v.x; A_s[r][k4 * 4 + 1] = v.y;
            A_s[r][k4 * 4 + 2] = v.z; A_s[r][k4 * 4 + 3] = v.w;
        }
#pragma unroll
        for (int i = 0; i < 4; i++) {
            int idx = tid + i * 256;
            int gg = idx >> 3, k4 = idx & 7;
            float4 v = reinterpret_cast<const float4*>(Wih_w + (size_t)(col0 + gg) * K_IN + k0 + k4 * 4)[0];
            B_s[k4 * 4 + 0][gg] = v.x; B_s[k4 * 4 + 1][gg] = v.y;
            B_s[k4 * 4 + 2][gg] = v.z; B_s[k4 * 4 + 3][gg] = v.w;
        }
        __syncthreads();
#pragma unroll
        for (int kk = 0; kk < BK; kk++) {
            float4 bv = reinterpret_cast<const float4*>(&B_s[kk][tx * 4])[0];
#pragma unroll
            for (int i = 0; i < 8; i++) {
                float av = A_s[tyy * 8 + i][kk];
                acc[i][0] += av * bv.x; acc[i][1] += av * bv.y;
                acc[i][2] += av * bv.z; acc[i][3] += av * bv.w;
            }
        }
        __syncthreads();
    }
#pragma unroll
    for (int i = 0; i < 8; i++) {
        int tb = row0 + tyy * 8 + i;
        int t = tb >> 6, b = tb & 63;
        int wb = b >> 2, rr = b & 3;
#pragma unroll
        for (int jv = 0; jv < 4; jv++) {
            int cg = col0 + tx * 4 + jv;
            int gt = cg >> 8, jj = cg & 255;
            int w2 = jj >> 5, jg = (jj >> 4) & 1, l15v = jj & 15;
            int nt = gt * 2 + jg;
            size_t idx = (((((size_t)t * 16 + wb) * 8 + w2) * 16 + l15v) * 8 + nt) * 4 + rr;
            xw6[idx] = f2bfu(acc[i][jv] + bih_w[cg] + bhh_w[cg]);
        }
    }
}

// ---------------- K4: word LSTM. 16 blocks x 4 chains, 512 threads (8 waves).
// Wave w owns all 4 gate types for dims j in [w*32, w*32+32) (nt = gt*2 + jg).
// Whh i8 register-resident (128 VGPR/lane); h via 4KB i8 A-pack, dbuf, 1 barrier/step.
__global__ __launch_bounds__(512, 1) void word_lstm(
        const unsigned short* __restrict__ xw6, const signed char* __restrict__ wq,
        const float* __restrict__ sw, float* __restrict__ h_out) {
    int wb   = blockIdx.x;               // chains [wb*4, wb*4+4)
    int tid  = threadIdx.x;
    int lane = tid & 63, w = tid >> 6;   // 8 waves
    int l15  = lane & 15, lq = lane >> 4;

    __shared__ long ha[2][512];          // A-pack [kt][lane], 8 i8 each, dbuf, 8 KB

    long bfr[8][8];
    float swl[8];
#pragma unroll
    for (int nt = 0; nt < 8; nt++) {
        int g = (nt >> 1) * 256 + w * 32 + (nt & 1) * 16 + l15;
        swl[nt] = sw[g] * (1.f / 127.f);
#pragma unroll
        for (int kt = 0; kt < 8; kt++)
            bfr[nt][kt] = *reinterpret_cast<const long*>(wq + (size_t)g * HID + kt * 32 + lq * 8);
    }
    ha[0][tid] = 0;
    ha[1][tid] = 0;
    float cst[8] = {0.f, 0.f, 0.f, 0.f, 0.f, 0.f, 0.f, 0.f};
    __syncthreads();

    for (int t = 0; t < SENT_LEN; t++) {
        // xw pre-activations: per-lane contiguous 64B (issued now, used after MFMA)
        const uint4* xp = reinterpret_cast<const uint4*>(
            xw6 + ((((size_t)t * 16 + wb) * 8 + w) * 16 + l15) * 32);
        uint4 xv0 = xp[0], xv1 = xp[1], xv2 = xp[2], xv3 = xp[3];

        const long* hc = ha[t & 1];
        i32x4 acc[8] = {};
#pragma unroll
        for (int kt = 0; kt < 8; kt++) {
            long a = hc[kt * 64 + lane];
#pragma unroll
            for (int nt = 0; nt < 8; nt++)
                acc[nt] = __builtin_amdgcn_mfma_i32_16x16x32_i8(a, bfr[nt][kt], acc[nt], 0, 0, 0);
        }

        unsigned short xs[32];
        *reinterpret_cast<uint4*>(&xs[0])  = xv0;
        *reinterpret_cast<uint4*>(&xs[8])  = xv1;
        *reinterpret_cast<uint4*>(&xs[16]) = xv2;
        *reinterpret_cast<uint4*>(&xs[24]) = xv3;

        signed char* hn = reinterpret_cast<signed char*>(ha[(t + 1) & 1]);
#pragma unroll
        for (int jg = 0; jg < 2; jg++) {
#pragma unroll
            for (int r = 0; r < 4; r++) {      // chain = wb*4 + r (real at lq==0)
                float gi = (float)acc[0 + jg][r] * swl[0 + jg] + bfu2f(xs[(0 + jg) * 4 + r]);
                float gf = (float)acc[2 + jg][r] * swl[2 + jg] + bfu2f(xs[(2 + jg) * 4 + r]);
                float gg = (float)acc[4 + jg][r] * swl[4 + jg] + bfu2f(xs[(4 + jg) * 4 + r]);
                float go = (float)acc[6 + jg][r] * swl[6 + jg] + bfu2f(xs[(6 + jg) * 4 + r]);
                float c = sigf(gf) * cst[jg * 4 + r] + sigf(gi) * tanhf_fast(gg);
                cst[jg * 4 + r] = c;
                float h = sigf(go) * tanhf_fast(c);
                if (lq == 0) {
                    int j = w * 32 + jg * 16 + l15;
                    int b = wb * 4 + r;
                    h_out[((size_t)t * SENT_BATCH + b) * HID + j] = h;
                    int qi = __float2int_rn(h * 127.f);
                    qi = qi > 127 ? 127 : (qi < -127 ? -127 : qi);
                    hn[(((j >> 5) * 64) + ((j >> 3) & 3) * 16 + r) * 8 + (j & 7)] = (signed char)qi;
                }
            }
        }
        __syncthreads();
    }
}

// ---------------- K5: tag projection + log_softmax.
__global__ __launch_bounds__(256) void tag_logsoftmax(
        const float* __restrict__ h_out, const float* __restrict__ W_tag,
        const float* __restrict__ b_tag, float* __restrict__ out) {
    __shared__ float wt_s[TAGS * 257];
    __shared__ float hr_s[4 * HID];
    int tid = threadIdx.x;
    int row0 = blockIdx.x * 4;
#pragma unroll 2
    for (int i = 0; i < TAGS; i++) wt_s[i * 257 + tid] = W_tag[i * HID + tid];
#pragma unroll
    for (int w = 0; w < 4; w++) hr_s[w * HID + tid] = h_out[(size_t)(row0 + w) * HID + tid];
    __syncthreads();

    int w = tid >> 6, l = tid & 63;
    float acc = 0.f;
    if (l < TAGS) {
        acc = b_tag[l];
        const float* hr = hr_s + w * HID;
        const float* wr = wt_s + l * 257;
#pragma unroll 4
        for (int k = 0; k < HID; k++) acc += hr[k] * wr[k];
    }
    float m = (l < TAGS) ? acc : -1e30f;
#pragma unroll
    for (int off = 32; off; off >>= 1) m = fmaxf(m, __shfl_xor(m, off, 64));
    float e = (l < TAGS) ? __expf(acc - m) : 0.f;
    float ssum = e;
#pragma unroll
    for (int off = 32; off; off >>= 1) ssum += __shfl_xor(ssum, off, 64);
    float lse = m + __logf(ssum);
    if (l < TAGS) out[(size_t)(row0 + w) * TAGS + l] = acc - lse;
}

extern "C" void kernel_launch(void* const* d_in, const int* in_sizes, int n_in,
                              void* d_out, int out_size, void* d_ws, size_t ws_size,
                              hipStream_t stream) {
    (void)in_sizes; (void)n_in; (void)out_size; (void)ws_size;
    const int*   sentences = (const int*)d_in[0];
    const int*   words     = (const int*)d_in[1];
    const float* word_emb  = (const float*)d_in[4];
    const float* char_emb  = (const float*)d_in[5];
    const float* Wih_c     = (const float*)d_in[6];
    const float* Whh_c     = (const float*)d_in[7];
    const float* bih_c     = (const float*)d_in[8];
    const float* bhh_c     = (const float*)d_in[9];
    const float* Wih_w     = (const float*)d_in[10];
    const float* Whh_w     = (const float*)d_in[11];
    const float* bih_w     = (const float*)d_in[12];
    const float* bhh_w     = (const float*)d_in[13];
    const float* W_tag     = (const float*)d_in[14];
    const float* b_tag     = (const float*)d_in[15];
    float* out = (float*)d_out;

    char* ws = (char*)d_ws;
    size_t off = 0;
    float* pre8 = (float*)(ws + off);                 off += 128 * 512 * sizeof(float);      // 256 KB
    signed char* wq = (signed char*)(ws + off);       off += 1024 * 256;                     // 256 KB
    float* sw = (float*)(ws + off);                   off += 1024 * sizeof(float);           // 4 KB
    off = (off + 255) & ~(size_t)255;
    float* cf = (float*)(ws + off);                   off += (size_t)SENT_LEN * SENT_BATCH * CHID * sizeof(float); // 8.4 MB
    unsigned short* xw6 = (unsigned short*)(ws + off); off += (size_t)SENT_LEN * SENT_BATCH * 1024 * sizeof(unsigned short); // 33.5 MB
    float* h_out = (float*)(ws + off);                off += (size_t)SENT_LEN * SENT_BATCH * HID * sizeof(float); // 16.8 MB

    hipLaunchKernelGGL(prep_char, dim3(128), dim3(512), 0, stream,
                       Wih_c, char_emb, bih_c, bhh_c, pre8);
    hipLaunchKernelGGL(prep_wq, dim3(1024), dim3(64), 0, stream, Whh_w, wq, sw);
    hipLaunchKernelGGL(char_lstm, dim3(64), dim3(512), 0, stream,
                       words, Whh_c, pre8, cf);
    hipLaunchKernelGGL(xw_gemm, dim3(1024 / BN, (SENT_LEN * SENT_BATCH) / BM), dim3(256), 0, stream,
                       sentences, word_emb, cf, Wih_w, bih_w, bhh_w, xw6);
    hipLaunchKernelGGL(word_lstm, dim3(16), dim3(512), 0, stream,
                       xw6, wq, sw, h_out);
    hipLaunchKernelGGL(tag_logsoftmax, dim3((SENT_LEN * SENT_BATCH) / 4), dim3(256), 0, stream,
                       h_out, W_tag, b_tag, out);
}

// Round 5
// 1426.166 us; speedup vs baseline: 2.7181x; 2.1600x over previous
//
#include <hip/hip_runtime.h>
#include <hip/hip_bf16.h>
#include <cstdint>

#define SENT_LEN   256
#define SENT_BATCH 64
#define WORD_LEN   16
#define EMB        128
#define HID        256
#define CEMB       64
#define CHID       128
#define TAGS       50
#define K_IN       (EMB + CHID)   // 256

typedef __attribute__((ext_vector_type(8))) short short8;
typedef __attribute__((ext_vector_type(4))) float f32x4;
typedef __attribute__((ext_vector_type(4))) int   i32x4;

__device__ __forceinline__ float sigf(float x) {
    return 1.f / (1.f + __expf(-x));
}
__device__ __forceinline__ float tanhf_fast(float x) {
    x = fminf(fmaxf(x, -15.f), 15.f);
    float e = __expf(2.f * x);
    return (e - 1.f) / (e + 1.f);
}
__device__ __forceinline__ float bf_lo(unsigned u) { return __uint_as_float(u << 16); }
__device__ __forceinline__ float bf_hi(unsigned u) { return __uint_as_float(u & 0xffff0000u); }
__device__ __forceinline__ unsigned short f2bfu(float f) {
    __hip_bfloat16 h = __float2bfloat16(f);
    return *reinterpret_cast<unsigned short*>(&h);
}
// CK-style barrier: drains LDS (lgkmcnt) only — global prefetches stay in flight.
__device__ __forceinline__ void block_sync_lds() {
    asm volatile("s_waitcnt lgkmcnt(0)\ns_barrier" ::: "memory");
}

// ---------------- K1a: pre8[(ch*128 + j)*4 + gt] = b_c[g] + Wih_c[g]·char_emb[ch], g = gt*128+j
__global__ void prep_char(const float* __restrict__ Wih_c, const float* __restrict__ char_emb,
                          const float* __restrict__ bih_c, const float* __restrict__ bhh_c,
                          float* __restrict__ pre8) {
    int ch = blockIdx.x;      // 128
    int g  = threadIdx.x;     // 512
    float acc = bih_c[g] + bhh_c[g];
    const float* w = Wih_c + g * CEMB;
    const float* e = char_emb + ch * CEMB;
#pragma unroll
    for (int k = 0; k < CEMB; k++) acc += w[k] * e[k];
    int gt = g >> 7, j = g & 127;
    pre8[((ch * 128) + j) * 4 + gt] = acc;
}

// ---------------- K1b: per-row i8 quantization of Whh_w. 1024 blocks x 64.
__global__ void prep_wq(const float* __restrict__ Whh_w, signed char* __restrict__ wq,
                        float* __restrict__ sw) {
    int g = blockIdx.x;
    int lane = threadIdx.x;   // 64
    float4 v = reinterpret_cast<const float4*>(Whh_w + (size_t)g * HID)[lane];
    float m = fmaxf(fmaxf(fabsf(v.x), fabsf(v.y)), fmaxf(fabsf(v.z), fabsf(v.w)));
#pragma unroll
    for (int off = 32; off; off >>= 1) m = fmaxf(m, __shfl_xor(m, off, 64));
    m = fmaxf(m, 1e-20f);
    float inv = 127.f / m;
    int q0 = __float2int_rn(v.x * inv), q1 = __float2int_rn(v.y * inv);
    int q2 = __float2int_rn(v.z * inv), q3 = __float2int_rn(v.w * inv);
    int packed = (q0 & 255) | ((q1 & 255) << 8) | ((q2 & 255) << 16) | ((q3 & 255) << 24);
    reinterpret_cast<int*>(wq)[g * 64 + lane] = packed;
    if (lane == 0) sw[g] = m / 127.f;
}

// ---------------- K2: char LSTM. 256 blocks x 1 chain, 512 threads (8 waves).
// Wave w owns gates i,f,g,o for dims j = w*16 + l15. Only M-row 0 is real:
// nonlin = ONE gate-set per lane. h via 4KB bf16 A-pack, dbuf, 1 lgkm-only barrier/step.
__global__ __launch_bounds__(512, 1) void char_lstm(
        const int* __restrict__ words, const float* __restrict__ Whh_c,
        const float* __restrict__ pre8, float* __restrict__ cf) {
    int t    = blockIdx.x;               // chain
    int tid  = threadIdx.x;
    int lane = tid & 63, w = tid >> 6;   // 8 waves
    int l15  = lane & 15, lq = lane >> 4;
    int j    = w * 16 + l15;

    __shared__ short8 ha[2][256];        // A-pack [kt][lane], dbuf, 8 KB

    // B-frags: nt = gate type; g = nt*128 + j; k = kt*32 + lq*8 + jj
    short8 bfr[4][4];
#pragma unroll
    for (int nt = 0; nt < 4; nt++) {
        const float* wr = Whh_c + (size_t)(nt * 128 + j) * CHID;
#pragma unroll
        for (int kt = 0; kt < 4; kt++) {
            float4 v0 = reinterpret_cast<const float4*>(wr + kt * 32 + lq * 8)[0];
            float4 v1 = reinterpret_cast<const float4*>(wr + kt * 32 + lq * 8 + 4)[0];
            short8 b;
            b[0] = (short)f2bfu(v0.x); b[1] = (short)f2bfu(v0.y);
            b[2] = (short)f2bfu(v0.z); b[3] = (short)f2bfu(v0.w);
            b[4] = (short)f2bfu(v1.x); b[5] = (short)f2bfu(v1.y);
            b[6] = (short)f2bfu(v1.z); b[7] = (short)f2bfu(v1.w);
            bfr[nt][kt] = b;
        }
    }
    {   // zero both A-pack buffers
        float4 z = {0.f, 0.f, 0.f, 0.f};
        reinterpret_cast<float4*>(ha)[tid] = z;
    }
    float cst = 0.f;
    int cid = words[t];                  // s=0
    __syncthreads();

    for (int s = 0; s < SENT_BATCH * WORD_LEN; s++) {
        // this step's pre-activation (cid from last iter); next step's cid (uniform s_load)
        float4 pr = reinterpret_cast<const float4*>(pre8)[cid * 128 + j];
        cid = words[((s + 1) & (SENT_BATCH * WORD_LEN - 1)) * SENT_LEN + t];

        const short8* hc = ha[s & 1];
        f32x4 acc[4] = {{0.f,0.f,0.f,0.f},{0.f,0.f,0.f,0.f},{0.f,0.f,0.f,0.f},{0.f,0.f,0.f,0.f}};
#pragma unroll
        for (int kt = 0; kt < 4; kt++) {
            short8 a = hc[kt * 64 + lane];
#pragma unroll
            for (int nt = 0; nt < 4; nt++)
                acc[nt] = __builtin_amdgcn_mfma_f32_16x16x32_bf16(a, bfr[nt][kt], acc[nt], 0, 0, 0);
        }

        // nonlinearity: M-row 0 only (real in lq==0 lanes; others ride along)
        float gi = acc[0][0] + pr.x;
        float gf = acc[1][0] + pr.y;
        float gg = acc[2][0] + pr.z;
        float go = acc[3][0] + pr.w;
        float c = sigf(gf) * cst + sigf(gi) * tanhf_fast(gg);
        cst = c;
        float h = sigf(go) * tanhf_fast(c);

        unsigned short* hn = reinterpret_cast<unsigned short*>(ha[(s + 1) & 1]);
        if (lq == 0) {
            // A-pack slot (m=0, k=j)
            hn[(((j >> 5) * 64) + ((j >> 3) & 3) * 16) * 8 + (j & 7)] = f2bfu(h);
            if ((s & 15) == 15)
                cf[((size_t)t * SENT_BATCH + (s >> 4)) * CHID + j] = h;
        }
        block_sync_lds();
    }
}

// ---------------- K3: xw8[(tb*256 + j)] = uint2{bf16 gates i,f,g,o} (gate-interleaved).
#define BM 64
#define BK 32
__global__ __launch_bounds__(256) void xw_gemm(
        const int* __restrict__ sentences, const float* __restrict__ word_emb,
        const float* __restrict__ cf, const float* __restrict__ Wih_w,
        const float* __restrict__ bih_w, const float* __restrict__ bhh_w,
        uint2* __restrict__ xw8) {
    __shared__ float A_s[BM][BK + 1];
    __shared__ float B_s[BK][132];       // column cc = (j-j0)*4 + gt
    __shared__ int sid_s[BM];
    int tid = threadIdx.x;
    int row0 = blockIdx.y * BM;
    int j0 = blockIdx.x * 32;
    if (tid < BM) sid_s[tid] = sentences[row0 + tid];
    __syncthreads();

    float acc[8][4] = {};
    int tx = tid & 31, tyy = tid >> 5;

    for (int k0 = 0; k0 < K_IN; k0 += BK) {
#pragma unroll
        for (int i = 0; i < 2; i++) {  // A tile: 64x32 = 512 float4
            int idx = tid + i * 256;
            int r = idx >> 3, k4 = idx & 7;
            int k = k0 + k4 * 4;
            float4 v;
            if (k < EMB)
                v = reinterpret_cast<const float4*>(word_emb + (size_t)sid_s[r] * EMB + k)[0];
            else
                v = reinterpret_cast<const float4*>(cf + (size_t)(row0 + r) * CHID + (k - EMB))[0];
            A_s[r][k4 * 4 + 0] = v.x; A_s[r][k4 * 4 + 1] = v.y;
            A_s[r][k4 * 4 + 2] = v.z; A_s[r][k4 * 4 + 3] = v.w;
        }
#pragma unroll
        for (int i = 0; i < 4; i++) {  // B tile: 128 cols x 32 k = 1024 float4
            int idx = tid + i * 256;
            int c = idx >> 3, k4 = idx & 7;
            int g = (c >> 5) * 256 + j0 + (c & 31);
            float4 v = reinterpret_cast<const float4*>(Wih_w + (size_t)g * K_IN + k0 + k4 * 4)[0];
            int cc = (c & 31) * 4 + (c >> 5);
            B_s[k4 * 4 + 0][cc] = v.x; B_s[k4 * 4 + 1][cc] = v.y;
            B_s[k4 * 4 + 2][cc] = v.z; B_s[k4 * 4 + 3][cc] = v.w;
        }
        __syncthreads();
#pragma unroll
        for (int kk = 0; kk < BK; kk++) {
            float4 bv = reinterpret_cast<const float4*>(&B_s[kk][tx * 4])[0];
#pragma unroll
            for (int i = 0; i < 8; i++) {
                float av = A_s[tyy * 8 + i][kk];
                acc[i][0] += av * bv.x; acc[i][1] += av * bv.y;
                acc[i][2] += av * bv.z; acc[i][3] += av * bv.w;
            }
        }
        __syncthreads();
    }
    float b0 = bih_w[0 * 256 + j0 + tx] + bhh_w[0 * 256 + j0 + tx];
    float b1 = bih_w[1 * 256 + j0 + tx] + bhh_w[1 * 256 + j0 + tx];
    float b2 = bih_w[2 * 256 + j0 + tx] + bhh_w[2 * 256 + j0 + tx];
    float b3 = bih_w[3 * 256 + j0 + tx] + bhh_w[3 * 256 + j0 + tx];
#pragma unroll
    for (int i = 0; i < 8; i++) {
        int tb = row0 + tyy * 8 + i;
        uint2 o;
        o.x = (unsigned)f2bfu(acc[i][0] + b0) | ((unsigned)f2bfu(acc[i][1] + b1) << 16);
        o.y = (unsigned)f2bfu(acc[i][2] + b2) | ((unsigned)f2bfu(acc[i][3] + b3) << 16);
        xw8[(size_t)tb * 256 + j0 + tx] = o;
    }
}

// ---------------- K4: word LSTM. 64 blocks x 1 chain, 512 threads (8 waves).
// Wave w owns dims [w*32, w*32+32), nt = gt*2+jg. Whh i8 register-resident.
// Only M-row 0 real: nonlin = 2 gate-sets/lane. xw prefetched 1 step ahead.
__global__ __launch_bounds__(512, 1) void word_lstm(
        const uint2* __restrict__ xw8, const signed char* __restrict__ wq,
        const float* __restrict__ sw, float* __restrict__ h_out) {
    int b    = blockIdx.x;               // chain 0..63
    int tid  = threadIdx.x;
    int lane = tid & 63, w = tid >> 6;   // 8 waves
    int l15  = lane & 15, lq = lane >> 4;

    __shared__ long ha[2][512];          // A-pack [kt][lane], 8 i8 each, dbuf, 8 KB

    long bfr[8][8];
    float swl[8];
#pragma unroll
    for (int nt = 0; nt < 8; nt++) {
        int g = (nt >> 1) * 256 + w * 32 + (nt & 1) * 16 + l15;
        swl[nt] = sw[g] * (1.f / 127.f);
#pragma unroll
        for (int kt = 0; kt < 8; kt++)
            bfr[nt][kt] = *reinterpret_cast<const long*>(wq + (size_t)g * HID + kt * 32 + lq * 8);
    }
    reinterpret_cast<long*>(ha)[tid] = 0;
    reinterpret_cast<long*>(ha)[tid + 512] = 0;
    float cst[2] = {0.f, 0.f};
    uint2 xq[2];
#pragma unroll
    for (int jg = 0; jg < 2; jg++)
        xq[jg] = xw8[(size_t)b * 256 + w * 32 + jg * 16 + l15];   // t=0
    __syncthreads();

    for (int t = 0; t < SENT_LEN; t++) {
        uint2 xn[2];
        int tn = (t + 1) & (SENT_LEN - 1);
#pragma unroll
        for (int jg = 0; jg < 2; jg++)
            xn[jg] = xw8[((size_t)tn * SENT_BATCH + b) * 256 + w * 32 + jg * 16 + l15];

        const long* hc = ha[t & 1];
        i32x4 acc[8] = {};
#pragma unroll
        for (int kt = 0; kt < 8; kt++) {
            long a = hc[kt * 64 + lane];
#pragma unroll
            for (int nt = 0; nt < 8; nt++)
                acc[nt] = __builtin_amdgcn_mfma_i32_16x16x32_i8(a, bfr[nt][kt], acc[nt], 0, 0, 0);
        }

        signed char* hn = reinterpret_cast<signed char*>(ha[(t + 1) & 1]);
#pragma unroll
        for (int jg = 0; jg < 2; jg++) {   // M-row 0 only
            float gi = (float)acc[0 + jg][0] * swl[0 + jg] + bf_lo(xq[jg].x);
            float gf = (float)acc[2 + jg][0] * swl[2 + jg] + bf_hi(xq[jg].x);
            float gg = (float)acc[4 + jg][0] * swl[4 + jg] + bf_lo(xq[jg].y);
            float go = (float)acc[6 + jg][0] * swl[6 + jg] + bf_hi(xq[jg].y);
            float c = sigf(gf) * cst[jg] + sigf(gi) * tanhf_fast(gg);
            cst[jg] = c;
            float h = sigf(go) * tanhf_fast(c);
            if (lq == 0) {
                int j = w * 32 + jg * 16 + l15;
                h_out[((size_t)t * SENT_BATCH + b) * HID + j] = h;
                int qi = __float2int_rn(h * 127.f);
                qi = qi > 127 ? 127 : (qi < -127 ? -127 : qi);
                hn[(((j >> 5) * 64) + ((j >> 3) & 3) * 16) * 8 + (j & 7)] = (signed char)qi;
            }
        }
        xq[0] = xn[0]; xq[1] = xn[1];
        block_sync_lds();
    }
}

// ---------------- K5: tag projection + log_softmax.
__global__ __launch_bounds__(256) void tag_logsoftmax(
        const float* __restrict__ h_out, const float* __restrict__ W_tag,
        const float* __restrict__ b_tag, float* __restrict__ out) {
    __shared__ float wt_s[TAGS * 257];
    __shared__ float hr_s[4 * HID];
    int tid = threadIdx.x;
    int row0 = blockIdx.x * 4;
#pragma unroll 2
    for (int i = 0; i < TAGS; i++) wt_s[i * 257 + tid] = W_tag[i * HID + tid];
#pragma unroll
    for (int w = 0; w < 4; w++) hr_s[w * HID + tid] = h_out[(size_t)(row0 + w) * HID + tid];
    __syncthreads();

    int w = tid >> 6, l = tid & 63;
    float acc = 0.f;
    if (l < TAGS) {
        acc = b_tag[l];
        const float* hr = hr_s + w * HID;
        const float* wr = wt_s + l * 257;
#pragma unroll 4
        for (int k = 0; k < HID; k++) acc += hr[k] * wr[k];
    }
    float m = (l < TAGS) ? acc : -1e30f;
#pragma unroll
    for (int off = 32; off; off >>= 1) m = fmaxf(m, __shfl_xor(m, off, 64));
    float e = (l < TAGS) ? __expf(acc - m) : 0.f;
    float ssum = e;
#pragma unroll
    for (int off = 32; off; off >>= 1) ssum += __shfl_xor(ssum, off, 64);
    float lse = m + __logf(ssum);
    if (l < TAGS) out[(size_t)(row0 + w) * TAGS + l] = acc - lse;
}

extern "C" void kernel_launch(void* const* d_in, const int* in_sizes, int n_in,
                              void* d_out, int out_size, void* d_ws, size_t ws_size,
                              hipStream_t stream) {
    (void)in_sizes; (void)n_in; (void)out_size; (void)ws_size;
    const int*   sentences = (const int*)d_in[0];
    const int*   words     = (const int*)d_in[1];
    const float* word_emb  = (const float*)d_in[4];
    const float* char_emb  = (const float*)d_in[5];
    const float* Wih_c     = (const float*)d_in[6];
    const float* Whh_c     = (const float*)d_in[7];
    const float* bih_c     = (const float*)d_in[8];
    const float* bhh_c     = (const float*)d_in[9];
    const float* Wih_w     = (const float*)d_in[10];
    const float* Whh_w     = (const float*)d_in[11];
    const float* bih_w     = (const float*)d_in[12];
    const float* bhh_w     = (const float*)d_in[13];
    const float* W_tag     = (const float*)d_in[14];
    const float* b_tag     = (const float*)d_in[15];
    float* out = (float*)d_out;

    char* ws = (char*)d_ws;
    size_t off = 0;
    float* pre8 = (float*)(ws + off);                 off += 128 * 512 * sizeof(float);      // 256 KB
    signed char* wq = (signed char*)(ws + off);       off += 1024 * 256;                     // 256 KB
    float* sw = (float*)(ws + off);                   off += 1024 * sizeof(float);           // 4 KB
    off = (off + 255) & ~(size_t)255;
    float* cf = (float*)(ws + off);                   off += (size_t)SENT_LEN * SENT_BATCH * CHID * sizeof(float); // 8.4 MB
    uint2* xw8 = (uint2*)(ws + off);                  off += (size_t)SENT_LEN * SENT_BATCH * 256 * sizeof(uint2);  // 33.5 MB
    float* h_out = (float*)(ws + off);                off += (size_t)SENT_LEN * SENT_BATCH * HID * sizeof(float);  // 16.8 MB

    hipLaunchKernelGGL(prep_char, dim3(128), dim3(512), 0, stream,
                       Wih_c, char_emb, bih_c, bhh_c, pre8);
    hipLaunchKernelGGL(prep_wq, dim3(1024), dim3(64), 0, stream, Whh_w, wq, sw);
    hipLaunchKernelGGL(char_lstm, dim3(256), dim3(512), 0, stream,
                       words, Whh_c, pre8, cf);
    hipLaunchKernelGGL(xw_gemm, dim3(8, (SENT_LEN * SENT_BATCH) / BM), dim3(256), 0, stream,
                       sentences, word_emb, cf, Wih_w, bih_w, bhh_w, xw8);
    hipLaunchKernelGGL(word_lstm, dim3(SENT_BATCH), dim3(512), 0, stream,
                       xw8, wq, sw, h_out);
    hipLaunchKernelGGL(tag_logsoftmax, dim3((SENT_LEN * SENT_BATCH) / 4), dim3(256), 0, stream,
                       h_out, W_tag, b_tag, out);
}

// Round 6
// 1196.843 us; speedup vs baseline: 3.2388x; 1.1916x over previous
//
#include <hip/hip_runtime.h>
#include <hip/hip_bf16.h>
#include <cstdint>

#define SENT_LEN   256
#define SENT_BATCH 64
#define WORD_LEN   16
#define EMB        128
#define HID        256
#define CEMB       64
#define CHID       128
#define TAGS       50
#define K_IN       (EMB + CHID)   // 256
#define LOG2E      1.44269504f

typedef __attribute__((ext_vector_type(8))) short short8;
typedef __attribute__((ext_vector_type(4))) float f32x4;
typedef __attribute__((ext_vector_type(4))) int   i32x4;

__device__ __forceinline__ float rcpf(float x) { return __builtin_amdgcn_rcpf(x); }
// inputs pre-scaled by log2e: sig2(xl) = sigmoid(xl/log2e), tanh2(xl) = tanh(xl/log2e)
__device__ __forceinline__ float sig2(float xl) {
    return rcpf(1.f + __builtin_amdgcn_exp2f(-xl));
}
__device__ __forceinline__ float tanh2(float xl) {
    xl = fminf(fmaxf(xl, -22.f), 22.f);
    float u = __builtin_amdgcn_exp2f(xl + xl);
    return (u - 1.f) * rcpf(u + 1.f);
}
__device__ __forceinline__ float bf_lo(unsigned u) { return __uint_as_float(u << 16); }
__device__ __forceinline__ float bf_hi(unsigned u) { return __uint_as_float(u & 0xffff0000u); }
// branch-free RNE bf16 (finite inputs only)
__device__ __forceinline__ unsigned short f2bfu(float f) {
    unsigned u = __float_as_uint(f);
    u += 0x7fff + ((u >> 16) & 1);
    return (unsigned short)(u >> 16);
}
// CK-style barrier: drains LDS (lgkmcnt) only — global prefetches stay in flight.
__device__ __forceinline__ void block_sync_lds() {
    asm volatile("s_waitcnt lgkmcnt(0)\ns_barrier" ::: "memory");
}

// ---------------- K1a: pre8[(ch*128+j)*4+gt] = LOG2E*(b_c[g] + Wih_c[g]·char_emb[ch]), g=gt*128+j
__global__ void prep_char(const float* __restrict__ Wih_c, const float* __restrict__ char_emb,
                          const float* __restrict__ bih_c, const float* __restrict__ bhh_c,
                          float* __restrict__ pre8) {
    int ch = blockIdx.x;      // 128
    int g  = threadIdx.x;     // 512
    float acc = bih_c[g] + bhh_c[g];
    const float* w = Wih_c + g * CEMB;
    const float* e = char_emb + ch * CEMB;
#pragma unroll
    for (int k = 0; k < CEMB; k++) acc += w[k] * e[k];
    int gt = g >> 7, j = g & 127;
    pre8[((ch * 128) + j) * 4 + gt] = acc * LOG2E;
}

// ---------------- K1b: per-row i8 quantization of Whh_w. 1024 blocks x 64.
__global__ void prep_wq(const float* __restrict__ Whh_w, signed char* __restrict__ wq,
                        float* __restrict__ sw) {
    int g = blockIdx.x;
    int lane = threadIdx.x;   // 64
    float4 v = reinterpret_cast<const float4*>(Whh_w + (size_t)g * HID)[lane];
    float m = fmaxf(fmaxf(fabsf(v.x), fabsf(v.y)), fmaxf(fabsf(v.z), fabsf(v.w)));
#pragma unroll
    for (int off = 32; off; off >>= 1) m = fmaxf(m, __shfl_xor(m, off, 64));
    m = fmaxf(m, 1e-20f);
    float inv = 127.f / m;
    int q0 = __float2int_rn(v.x * inv), q1 = __float2int_rn(v.y * inv);
    int q2 = __float2int_rn(v.z * inv), q3 = __float2int_rn(v.w * inv);
    int packed = (q0 & 255) | ((q1 & 255) << 8) | ((q2 & 255) << 16) | ((q3 & 255) << 24);
    reinterpret_cast<int*>(wq)[g * 64 + lane] = packed;
    if (lane == 0) sw[g] = m / 127.f;
}

// ---------------- K2: char LSTM. 256 blocks x 1 chain, 512 threads (8 waves).
__global__ __launch_bounds__(512, 1) void char_lstm(
        const int* __restrict__ words, const float* __restrict__ Whh_c,
        const float* __restrict__ pre8, float* __restrict__ cf) {
    int t    = blockIdx.x;               // chain
    int tid  = threadIdx.x;
    int lane = tid & 63, w = tid >> 6;   // 8 waves
    int l15  = lane & 15, lq = lane >> 4;
    int j    = w * 16 + l15;

    __shared__ short8 ha[2][256];        // A-pack [kt][lane], dbuf, 8 KB

    // B-frags (log2e-scaled): nt = gate type; g = nt*128 + j; k = kt*32 + lq*8 + jj
    short8 bfr[4][4];
#pragma unroll
    for (int nt = 0; nt < 4; nt++) {
        const float* wr = Whh_c + (size_t)(nt * 128 + j) * CHID;
#pragma unroll
        for (int kt = 0; kt < 4; kt++) {
            float4 v0 = reinterpret_cast<const float4*>(wr + kt * 32 + lq * 8)[0];
            float4 v1 = reinterpret_cast<const float4*>(wr + kt * 32 + lq * 8 + 4)[0];
            short8 b;
            b[0] = (short)f2bfu(v0.x * LOG2E); b[1] = (short)f2bfu(v0.y * LOG2E);
            b[2] = (short)f2bfu(v0.z * LOG2E); b[3] = (short)f2bfu(v0.w * LOG2E);
            b[4] = (short)f2bfu(v1.x * LOG2E); b[5] = (short)f2bfu(v1.y * LOG2E);
            b[6] = (short)f2bfu(v1.z * LOG2E); b[7] = (short)f2bfu(v1.w * LOG2E);
            bfr[nt][kt] = b;
        }
    }
    {
        float4 z = {0.f, 0.f, 0.f, 0.f};
        reinterpret_cast<float4*>(ha)[tid] = z;
    }
    float cst = 0.f;
    int cid = words[t];                  // s=0
    __syncthreads();

    for (int s = 0; s < SENT_BATCH * WORD_LEN; s++) {
        float4 pr = reinterpret_cast<const float4*>(pre8)[cid * 128 + j];
        cid = words[((s + 1) & (SENT_BATCH * WORD_LEN - 1)) * SENT_LEN + t];

        const short8* hc = ha[s & 1];
        f32x4 acc[4] = {{0.f,0.f,0.f,0.f},{0.f,0.f,0.f,0.f},{0.f,0.f,0.f,0.f},{0.f,0.f,0.f,0.f}};
#pragma unroll
        for (int kt = 0; kt < 4; kt++) {
            short8 a = hc[kt * 64 + lane];
#pragma unroll
            for (int nt = 0; nt < 4; nt++)
                acc[nt] = __builtin_amdgcn_mfma_f32_16x16x32_bf16(a, bfr[nt][kt], acc[nt], 0, 0, 0);
        }

        // nonlinearity (log2e-scaled gates): M-row 0 only
        float gi = acc[0][0] + pr.x;
        float gf = acc[1][0] + pr.y;
        float gg = acc[2][0] + pr.z;
        float go = acc[3][0] + pr.w;
        float c = sig2(gf) * cst + sig2(gi) * tanh2(gg);
        cst = c;
        float h = sig2(go) * tanh2(c * LOG2E);

        unsigned short* hn = reinterpret_cast<unsigned short*>(ha[(s + 1) & 1]);
        if (lq == 0) {
            hn[(((j >> 5) * 64) + ((j >> 3) & 3) * 16) * 8 + (j & 7)] = f2bfu(h);
            if ((s & 15) == 15)
                cf[((size_t)t * SENT_BATCH + (s >> 4)) * CHID + j] = h;
        }
        block_sync_lds();
    }
}

// ---------------- K3: bf16 MFMA GEMM. xw8[tb*256+j] = uint2{bf16 LOG2E*(gates i,f | g,o)}.
// Grid (16, 256): bx = 16-dim j slice, by = 64-row tb slice. 256 thr = 4 waves (M-tiles).
#define XW_SEG 65   // 16B units per LDS segment (64 lanes + 1 pad)
__global__ __launch_bounds__(256, 2) void xw_gemm(
        const int* __restrict__ sentences, const float* __restrict__ word_emb,
        const float* __restrict__ cf, const float* __restrict__ Wih_w,
        const float* __restrict__ bih_w, const float* __restrict__ bhh_w,
        uint2* __restrict__ xw8) {
    __shared__ short8 Apack[32 * XW_SEG];   // segment s = kt*4 + wv(m-tile)
    __shared__ short8 Bpack[32 * XW_SEG];   // segment s = kt*4 + nt(gate type)
    __shared__ int sid_s[64];
    int tid = threadIdx.x;
    int j0 = blockIdx.x * 16;
    int row0 = blockIdx.y * 64;
    if (tid < 64) sid_s[tid] = sentences[row0 + tid];
    __syncthreads();

    // staging: 8 iters; chunk: m = idx>>5 (0..63), k8 = idx&31 (8-wide k chunk)
#pragma unroll
    for (int it = 0; it < 8; it++) {
        int idx = it * 256 + tid;
        int m = idx >> 5, k8 = idx & 31;
        int k = k8 * 8;
        int kt = k8 >> 2, lqs = k8 & 3;
        int lanes = (m & 15) + (lqs << 4);
        int seg = kt * 4 + (m >> 4);
        // A: x[row0+m][k] = k<128 ? word_emb[sid][k] : cf[row0+m][k-128]
        const float* asrc = (k < EMB)
            ? word_emb + (size_t)sid_s[m] * EMB + k
            : cf + (size_t)(row0 + m) * CHID + (k - EMB);
        float4 a0 = reinterpret_cast<const float4*>(asrc)[0];
        float4 a1 = reinterpret_cast<const float4*>(asrc)[1];
        short8 av;
        av[0] = (short)f2bfu(a0.x); av[1] = (short)f2bfu(a0.y);
        av[2] = (short)f2bfu(a0.z); av[3] = (short)f2bfu(a0.w);
        av[4] = (short)f2bfu(a1.x); av[5] = (short)f2bfu(a1.y);
        av[6] = (short)f2bfu(a1.z); av[7] = (short)f2bfu(a1.w);
        Apack[seg * XW_SEG + lanes] = av;
        // B: gate row g = (m>>4)*256 + j0 + (m&15)
        const float* bsrc = Wih_w + (size_t)((m >> 4) * 256 + j0 + (m & 15)) * K_IN + k;
        float4 b0 = reinterpret_cast<const float4*>(bsrc)[0];
        float4 b1 = reinterpret_cast<const float4*>(bsrc)[1];
        short8 bv;
        bv[0] = (short)f2bfu(b0.x); bv[1] = (short)f2bfu(b0.y);
        bv[2] = (short)f2bfu(b0.z); bv[3] = (short)f2bfu(b0.w);
        bv[4] = (short)f2bfu(b1.x); bv[5] = (short)f2bfu(b1.y);
        bv[6] = (short)f2bfu(b1.z); bv[7] = (short)f2bfu(b1.w);
        Bpack[seg * XW_SEG + lanes] = bv;
    }
    __syncthreads();

    int lane = tid & 63, wv = tid >> 6, l15 = lane & 15, lq = lane >> 4;
    f32x4 acc[4] = {{0.f,0.f,0.f,0.f},{0.f,0.f,0.f,0.f},{0.f,0.f,0.f,0.f},{0.f,0.f,0.f,0.f}};
#pragma unroll
    for (int kt = 0; kt < 8; kt++) {
        short8 a = Apack[(kt * 4 + wv) * XW_SEG + lane];
#pragma unroll
        for (int nt = 0; nt < 4; nt++)
            acc[nt] = __builtin_amdgcn_mfma_f32_16x16x32_bf16(
                a, Bpack[(kt * 4 + nt) * XW_SEG + lane], acc[nt], 0, 0, 0);
    }
    float bb[4];
#pragma unroll
    for (int nt = 0; nt < 4; nt++)
        bb[nt] = bih_w[nt * 256 + j0 + l15] + bhh_w[nt * 256 + j0 + l15];
#pragma unroll
    for (int r = 0; r < 4; r++) {
        int tb = row0 + wv * 16 + lq * 4 + r;
        uint2 o;
        o.x = (unsigned)f2bfu((acc[0][r] + bb[0]) * LOG2E)
            | ((unsigned)f2bfu((acc[1][r] + bb[1]) * LOG2E) << 16);
        o.y = (unsigned)f2bfu((acc[2][r] + bb[2]) * LOG2E)
            | ((unsigned)f2bfu((acc[3][r] + bb[3]) * LOG2E) << 16);
        xw8[(size_t)tb * 256 + j0 + l15] = o;
    }
}

// ---------------- K4: word LSTM. 64 blocks x 1 chain, 512 threads (8 waves).
__global__ __launch_bounds__(512, 1) void word_lstm(
        const uint2* __restrict__ xw8, const signed char* __restrict__ wq,
        const float* __restrict__ sw, float* __restrict__ h_out) {
    int b    = blockIdx.x;               // chain 0..63
    int tid  = threadIdx.x;
    int lane = tid & 63, w = tid >> 6;   // 8 waves
    int l15  = lane & 15, lq = lane >> 4;

    __shared__ long ha[2][512];          // A-pack [kt][lane], 8 i8 each, dbuf, 8 KB

    long bfr[8][8];
    float swl[8];
#pragma unroll
    for (int nt = 0; nt < 8; nt++) {
        int g = (nt >> 1) * 256 + w * 32 + (nt & 1) * 16 + l15;
        swl[nt] = sw[g] * (LOG2E / 127.f);
#pragma unroll
        for (int kt = 0; kt < 8; kt++)
            bfr[nt][kt] = *reinterpret_cast<const long*>(wq + (size_t)g * HID + kt * 32 + lq * 8);
    }
    reinterpret_cast<long*>(ha)[tid] = 0;
    reinterpret_cast<long*>(ha)[tid + 512] = 0;
    float cst[2] = {0.f, 0.f};
    uint2 xq[2];
#pragma unroll
    for (int jg = 0; jg < 2; jg++)
        xq[jg] = xw8[(size_t)b * 256 + w * 32 + jg * 16 + l15];   // t=0
    __syncthreads();

    for (int t = 0; t < SENT_LEN; t++) {
        uint2 xn[2];
        int tn = (t + 1) & (SENT_LEN - 1);
#pragma unroll
        for (int jg = 0; jg < 2; jg++)
            xn[jg] = xw8[((size_t)tn * SENT_BATCH + b) * 256 + w * 32 + jg * 16 + l15];

        const long* hc = ha[t & 1];
        i32x4 acc[8] = {};
#pragma unroll
        for (int kt = 0; kt < 8; kt++) {
            long a = hc[kt * 64 + lane];
#pragma unroll
            for (int nt = 0; nt < 8; nt++)
                acc[nt] = __builtin_amdgcn_mfma_i32_16x16x32_i8(a, bfr[nt][kt], acc[nt], 0, 0, 0);
        }

        signed char* hn = reinterpret_cast<signed char*>(ha[(t + 1) & 1]);
#pragma unroll
        for (int jg = 0; jg < 2; jg++) {   // M-row 0 only
            float gi = (float)acc[0 + jg][0] * swl[0 + jg] + bf_lo(xq[jg].x);
            float gf = (float)acc[2 + jg][0] * swl[2 + jg] + bf_hi(xq[jg].x);
            float gg = (float)acc[4 + jg][0] * swl[4 + jg] + bf_lo(xq[jg].y);
            float go = (float)acc[6 + jg][0] * swl[6 + jg] + bf_hi(xq[jg].y);
            float c = sig2(gf) * cst[jg] + sig2(gi) * tanh2(gg);
            cst[jg] = c;
            float h = sig2(go) * tanh2(c * LOG2E);
            if (lq == 0) {
                int j = w * 32 + jg * 16 + l15;
                h_out[((size_t)t * SENT_BATCH + b) * HID + j] = h;
                int qi = __float2int_rn(h * 127.f);
                qi = qi > 127 ? 127 : (qi < -127 ? -127 : qi);
                hn[(((j >> 5) * 64) + ((j >> 3) & 3) * 16) * 8 + (j & 7)] = (signed char)qi;
            }
        }
        xq[0] = xn[0]; xq[1] = xn[1];
        block_sync_lds();
    }
}

// ---------------- K5: tag projection + log_softmax.
__global__ __launch_bounds__(256) void tag_logsoftmax(
        const float* __restrict__ h_out, const float* __restrict__ W_tag,
        const float* __restrict__ b_tag, float* __restrict__ out) {
    __shared__ float wt_s[TAGS * 257];
    __shared__ float hr_s[4 * HID];
    int tid = threadIdx.x;
    int row0 = blockIdx.x * 4;
#pragma unroll 2
    for (int i = 0; i < TAGS; i++) wt_s[i * 257 + tid] = W_tag[i * HID + tid];
#pragma unroll
    for (int w = 0; w < 4; w++) hr_s[w * HID + tid] = h_out[(size_t)(row0 + w) * HID + tid];
    __syncthreads();

    int w = tid >> 6, l = tid & 63;
    float acc = 0.f;
    if (l < TAGS) {
        acc = b_tag[l];
        const float* hr = hr_s + w * HID;
        const float* wr = wt_s + l * 257;
#pragma unroll 4
        for (int k = 0; k < HID; k++) acc += hr[k] * wr[k];
    }
    float m = (l < TAGS) ? acc : -1e30f;
#pragma unroll
    for (int off = 32; off; off >>= 1) m = fmaxf(m, __shfl_xor(m, off, 64));
    float e = (l < TAGS) ? __builtin_amdgcn_exp2f((acc - m) * LOG2E) : 0.f;
    float ssum = e;
#pragma unroll
    for (int off = 32; off; off >>= 1) ssum += __shfl_xor(ssum, off, 64);
    float lse = m + __logf(ssum);
    if (l < TAGS) out[(size_t)(row0 + w) * TAGS + l] = acc - lse;
}

extern "C" void kernel_launch(void* const* d_in, const int* in_sizes, int n_in,
                              void* d_out, int out_size, void* d_ws, size_t ws_size,
                              hipStream_t stream) {
    (void)in_sizes; (void)n_in; (void)out_size; (void)ws_size;
    const int*   sentences = (const int*)d_in[0];
    const int*   words     = (const int*)d_in[1];
    const float* word_emb  = (const float*)d_in[4];
    const float* char_emb  = (const float*)d_in[5];
    const float* Wih_c     = (const float*)d_in[6];
    const float* Whh_c     = (const float*)d_in[7];
    const float* bih_c     = (const float*)d_in[8];
    const float* bhh_c     = (const float*)d_in[9];
    const float* Wih_w     = (const float*)d_in[10];
    const float* Whh_w     = (const float*)d_in[11];
    const float* bih_w     = (const float*)d_in[12];
    const float* bhh_w     = (const float*)d_in[13];
    const float* W_tag     = (const float*)d_in[14];
    const float* b_tag     = (const float*)d_in[15];
    float* out = (float*)d_out;

    char* ws = (char*)d_ws;
    size_t off = 0;
    float* pre8 = (float*)(ws + off);                 off += 128 * 512 * sizeof(float);      // 256 KB
    signed char* wq = (signed char*)(ws + off);       off += 1024 * 256;                     // 256 KB
    float* sw = (float*)(ws + off);                   off += 1024 * sizeof(float);           // 4 KB
    off = (off + 255) & ~(size_t)255;
    float* cf = (float*)(ws + off);                   off += (size_t)SENT_LEN * SENT_BATCH * CHID * sizeof(float); // 8.4 MB
    uint2* xw8 = (uint2*)(ws + off);                  off += (size_t)SENT_LEN * SENT_BATCH * 256 * sizeof(uint2);  // 33.5 MB
    float* h_out = (float*)(ws + off);                off += (size_t)SENT_LEN * SENT_BATCH * HID * sizeof(float);  // 16.8 MB

    hipLaunchKernelGGL(prep_char, dim3(128), dim3(512), 0, stream,
                       Wih_c, char_emb, bih_c, bhh_c, pre8);
    hipLaunchKernelGGL(prep_wq, dim3(1024), dim3(64), 0, stream, Whh_w, wq, sw);
    hipLaunchKernelGGL(char_lstm, dim3(256), dim3(512), 0, stream,
                       words, Whh_c, pre8, cf);
    hipLaunchKernelGGL(xw_gemm, dim3(16, 256), dim3(256), 0, stream,
                       sentences, word_emb, cf, Wih_w, bih_w, bhh_w, xw8);
    hipLaunchKernelGGL(word_lstm, dim3(SENT_BATCH), dim3(512), 0, stream,
                       xw8, wq, sw, h_out);
    hipLaunchKernelGGL(tag_logsoftmax, dim3((SENT_LEN * SENT_BATCH) / 4), dim3(256), 0, stream,
                       h_out, W_tag, b_tag, out);
}